// Round 1
// baseline (183.535 us; speedup 1.0000x reference)
//
#include <hip/hip_runtime.h>

// Problem constants
#define NB 8
#define NS 256
#define ND 64
#define NV 8192
#define CH 16       // s-chunk per bilinear block
#define BT_TILE 16  // bt rows per logits block

// h[b,s,d] = embed[x[b,s], d]   (131072 threads exactly)
__global__ __launch_bounds__(256) void k_gather(const int* __restrict__ x,
                                                const float* __restrict__ embed,
                                                float* __restrict__ h) {
    int tid = blockIdx.x * 256 + threadIdx.x;
    int bs = tid >> 6;
    int d  = tid & 63;
    h[tid] = embed[(size_t)x[bs] * ND + d];
}

// et[o][v] = embed[v][o]
__global__ __launch_bounds__(256) void k_transpose(const float* __restrict__ embed,
                                                   float* __restrict__ et) {
    __shared__ float tile[64][65];
    int vbase = blockIdx.x * 64;
    int o = threadIdx.x & 63;
    int r = threadIdx.x >> 6;  // 0..3
    for (int i = r; i < 64; i += 4)
        tile[i][o] = embed[(size_t)(vbase + i) * ND + o];
    __syncthreads();
    for (int i = r; i < 64; i += 4)
        et[(size_t)i * NV + vbase + o] = tile[o][i];
}

// y[b,t,o] += sum_{s in chunk, s<=t} sum_d h[b,s,d] * K[t,s,d,o]
__global__ __launch_bounds__(256) void k_bilinear(const float* __restrict__ h,
                                                  const float* __restrict__ K,
                                                  float* __restrict__ y) {
    int t  = blockIdx.x;
    int c  = blockIdx.y;
    int s0 = c * CH;
    if (s0 > t) return;                 // upper triangle: never fetch K
    int ns = min(t + 1 - s0, CH);

    __shared__ float smem[NB * CH * ND]; // 32 KB; reused for reduction

    // stage h[b, s0:s0+CH, :] -> LDS (contiguous per b, fully coalesced)
    for (int i = threadIdx.x; i < NB * CH * ND; i += 256) {
        int b   = i >> 10;       // / (CH*ND)
        int rem = i & 1023;
        smem[i] = h[((size_t)b * NS + s0) * ND + rem];
    }
    __syncthreads();

    int ot = threadIdx.x & 15;   // o-quad index
    int dg = threadIdx.x >> 4;   // d-group 0..15
    int o4 = ot * 4;
    int db = dg * 4;

    float4 acc[NB];
#pragma unroll
    for (int b = 0; b < NB; b++) acc[b] = make_float4(0.f, 0.f, 0.f, 0.f);

    const float* Kt = K + (size_t)t * NS * ND * ND;
    for (int si = 0; si < ns; si++) {
        const float* Ks = Kt + (size_t)(s0 + si) * ND * ND;
#pragma unroll
        for (int i = 0; i < 4; i++) {
            int d = db + i;
            float4 k4 = *reinterpret_cast<const float4*>(Ks + d * ND + o4);
#pragma unroll
            for (int b = 0; b < NB; b++) {
                float hv = smem[b * (CH * ND) + si * ND + d];
                acc[b].x += hv * k4.x;
                acc[b].y += hv * k4.y;
                acc[b].z += hv * k4.z;
                acc[b].w += hv * k4.w;
            }
        }
    }
    __syncthreads();

    // reduce the 16 d-groups via LDS, then atomic into y
    float4* red = reinterpret_cast<float4*>(smem);
#pragma unroll
    for (int b = 0; b < NB; b++) red[(dg * NB + b) * 16 + ot] = acc[b];
    __syncthreads();

    if (threadIdx.x < 128) {
        int b = threadIdx.x >> 4;
        int o = threadIdx.x & 15;
        float4 s = make_float4(0.f, 0.f, 0.f, 0.f);
#pragma unroll
        for (int g = 0; g < 16; g++) {
            float4 v = red[(g * NB + b) * 16 + o];
            s.x += v.x; s.y += v.y; s.z += v.z; s.w += v.w;
        }
        float* yp = y + ((size_t)b * NS + t) * ND + o * 4;
        atomicAdd(yp + 0, s.x);
        atomicAdd(yp + 1, s.y);
        atomicAdd(yp + 2, s.z);
        atomicAdd(yp + 3, s.w);
    }
}

// out[bt, v] = sum_o y[bt, o] * et[o][v]
__global__ __launch_bounds__(256) void k_logits(const float* __restrict__ y,
                                                const float* __restrict__ et,
                                                float* __restrict__ out) {
    int bt0 = blockIdx.x * BT_TILE;
    int v4  = blockIdx.y * 1024 + threadIdx.x * 4;

    __shared__ float ylds[BT_TILE][ND];
    for (int i = threadIdx.x; i < BT_TILE * ND; i += 256)
        ylds[i >> 6][i & 63] = y[(size_t)bt0 * ND + i];
    __syncthreads();

    float4 acc[BT_TILE];
#pragma unroll
    for (int r = 0; r < BT_TILE; r++) acc[r] = make_float4(0.f, 0.f, 0.f, 0.f);

#pragma unroll 4
    for (int o = 0; o < ND; o++) {
        float4 e4 = *reinterpret_cast<const float4*>(et + (size_t)o * NV + v4);
#pragma unroll
        for (int r = 0; r < BT_TILE; r++) {
            float yv = ylds[r][o];
            acc[r].x += yv * e4.x;
            acc[r].y += yv * e4.y;
            acc[r].z += yv * e4.z;
            acc[r].w += yv * e4.w;
        }
    }

#pragma unroll
    for (int r = 0; r < BT_TILE; r++)
        *reinterpret_cast<float4*>(out + (size_t)(bt0 + r) * NV + v4) = acc[r];
}

extern "C" void kernel_launch(void* const* d_in, const int* in_sizes, int n_in,
                              void* d_out, int out_size, void* d_ws, size_t ws_size,
                              hipStream_t stream) {
    const int*   x     = (const int*)d_in[0];
    const float* embed = (const float*)d_in[1];
    const float* K     = (const float*)d_in[2];
    float* out = (float*)d_out;

    float* h  = (float*)d_ws;          // 131072 f32 (512 KB)
    float* y  = h + NB * NS * ND;      // 131072 f32 (512 KB)
    float* et = y + NB * NS * ND;      // 524288 f32 (2 MB)

    hipMemsetAsync(y, 0, (size_t)NB * NS * ND * sizeof(float), stream);
    k_gather<<<dim3((NB * NS * ND) / 256), 256, 0, stream>>>(x, embed, h);
    k_transpose<<<dim3(NV / 64), 256, 0, stream>>>(embed, et);
    k_bilinear<<<dim3(NS, NS / CH), 256, 0, stream>>>(h, K, y);
    k_logits<<<dim3((NB * NS) / BT_TILE, NV / 1024), 256, 0, stream>>>(y, et, out);
}

// Round 3
// 158.641 us; speedup vs baseline: 1.1569x; 1.1569x over previous
//
#include <hip/hip_runtime.h>

// Problem constants
#define NB 8
#define NS 256
#define ND 64
#define NV 8192
#define CH 16       // s-chunk per bilinear block
#define BT_TILE 16  // bt rows per logits block
#define NCHUNK 2176 // sum over t of (t/16 + 1)

typedef float f32x4 __attribute__((ext_vector_type(4)));

// h[b,s,d] = embed[x[b,s], d]  and  y = 0   (131072 threads exactly)
__global__ __launch_bounds__(256) void k_init(const int* __restrict__ x,
                                              const float* __restrict__ embed,
                                              float* __restrict__ h,
                                              float* __restrict__ y) {
    int tid = blockIdx.x * 256 + threadIdx.x;
    int bs = tid >> 6;
    int d  = tid & 63;
    h[tid] = embed[(size_t)x[bs] * ND + d];
    y[tid] = 0.f;
}

// et[o][v] = embed[v][o]
__global__ __launch_bounds__(256) void k_transpose(const float* __restrict__ embed,
                                                   float* __restrict__ et) {
    __shared__ float tile[64][65];
    int vbase = blockIdx.x * 64;
    int o = threadIdx.x & 63;
    int r = threadIdx.x >> 6;  // 0..3
    for (int i = r; i < 64; i += 4)
        tile[i][o] = embed[(size_t)(vbase + i) * ND + o];
    __syncthreads();
    for (int i = r; i < 64; i += 4)
        et[(size_t)i * NV + vbase + o] = tile[o][i];
}

// y[b,t,o] += sum_{s in chunk, s<=t} sum_d h[b,s,d] * K[t,s,d,o]
// Exact triangular launch, longest-job-first (t descending).
__global__ __launch_bounds__(256) void k_bilinear(const float* __restrict__ h,
                                                  const float* __restrict__ K,
                                                  float* __restrict__ y) {
    // decode chunk id -> (t, c); L descending in t so blockIdx.x=0 is biggest
    int L = (NCHUNK - 1) - (int)blockIdx.x;
    int g = 0;
    while (8 * (g + 1) * (g + 2) <= L) g++;       // group g = t>>4, 16(g+1) chunks/group
    int rem = L - 8 * g * (g + 1);
    int tq  = rem / (g + 1);
    int t   = 16 * g + tq;
    int c   = rem - tq * (g + 1);
    int s0  = c * CH;
    int ns  = min(t + 1 - s0, CH);

    __shared__ float smem[NB * CH * ND]; // 32 KB; reused for reduction

    // stage h[b, s0:s0+CH, :] -> LDS (contiguous per b, fully coalesced)
    for (int i = threadIdx.x; i < NB * CH * ND; i += 256) {
        int b    = i >> 10;       // / (CH*ND)
        int rem2 = i & 1023;
        smem[i] = h[((size_t)b * NS + s0) * ND + rem2];
    }
    __syncthreads();

    int ot = threadIdx.x & 15;   // o-quad index
    int dg = threadIdx.x >> 4;   // d-group 0..15
    int o4 = ot * 4;
    int db = dg * 4;

    f32x4 acc[NB];
#pragma unroll
    for (int b = 0; b < NB; b++) acc[b] = (f32x4)(0.f);

    const float* Kt = K + (size_t)t * NS * ND * ND;
    for (int si = 0; si < ns; si++) {
        const float* Ks = Kt + (size_t)(s0 + si) * ND * ND;
#pragma unroll
        for (int i = 0; i < 4; i++) {
            int d = db + i;
            f32x4 k4 = __builtin_nontemporal_load(
                reinterpret_cast<const f32x4*>(Ks + d * ND + o4));
#pragma unroll
            for (int b = 0; b < NB; b++) {
                float hv = smem[b * (CH * ND) + si * ND + d];
                acc[b] += hv * k4;
            }
        }
    }
    __syncthreads();

    // reduce the 16 d-groups via LDS, then atomic into y
    f32x4* red = reinterpret_cast<f32x4*>(smem);
#pragma unroll
    for (int b = 0; b < NB; b++) red[(dg * NB + b) * 16 + ot] = acc[b];
    __syncthreads();

    if (threadIdx.x < 128) {
        int b = threadIdx.x >> 4;
        int o = threadIdx.x & 15;
        f32x4 s = (f32x4)(0.f);
#pragma unroll
        for (int gg = 0; gg < 16; gg++)
            s += red[(gg * NB + b) * 16 + o];
        float* yp = y + ((size_t)b * NS + t) * ND + o * 4;
        atomicAdd(yp + 0, s.x);
        atomicAdd(yp + 1, s.y);
        atomicAdd(yp + 2, s.z);
        atomicAdd(yp + 3, s.w);
    }
}

// out[bt, v] = sum_o y[bt, o] * et[o][v]
__global__ __launch_bounds__(256) void k_logits(const float* __restrict__ y,
                                                const float* __restrict__ et,
                                                float* __restrict__ out) {
    int bt0 = blockIdx.x * BT_TILE;
    int v4  = blockIdx.y * 1024 + threadIdx.x * 4;

    __shared__ float ylds[BT_TILE][ND];
    for (int i = threadIdx.x; i < BT_TILE * ND; i += 256)
        ylds[i >> 6][i & 63] = y[(size_t)bt0 * ND + i];
    __syncthreads();

    f32x4 acc[BT_TILE];
#pragma unroll
    for (int r = 0; r < BT_TILE; r++) acc[r] = (f32x4)(0.f);

#pragma unroll 4
    for (int o = 0; o < ND; o++) {
        f32x4 e4 = *reinterpret_cast<const f32x4*>(et + (size_t)o * NV + v4);
#pragma unroll
        for (int r = 0; r < BT_TILE; r++) {
            float yv = ylds[r][o];
            acc[r] += yv * e4;
        }
    }

#pragma unroll
    for (int r = 0; r < BT_TILE; r++)
        __builtin_nontemporal_store(acc[r],
            reinterpret_cast<f32x4*>(out + (size_t)(bt0 + r) * NV + v4));
}

extern "C" void kernel_launch(void* const* d_in, const int* in_sizes, int n_in,
                              void* d_out, int out_size, void* d_ws, size_t ws_size,
                              hipStream_t stream) {
    const int*   x     = (const int*)d_in[0];
    const float* embed = (const float*)d_in[1];
    const float* K     = (const float*)d_in[2];
    float* out = (float*)d_out;

    float* h  = (float*)d_ws;          // 131072 f32 (512 KB)
    float* y  = h + NB * NS * ND;      // 131072 f32 (512 KB)
    float* et = y + NB * NS * ND;      // 524288 f32 (2 MB)

    k_init<<<dim3((NB * NS * ND) / 256), 256, 0, stream>>>(x, embed, h, y);
    k_transpose<<<dim3(NV / 64), 256, 0, stream>>>(embed, et);
    k_bilinear<<<dim3(NCHUNK), 256, 0, stream>>>(h, K, y);
    k_logits<<<dim3((NB * NS) / BT_TILE, NV / 1024), 256, 0, stream>>>(y, et, out);
}